// Round 13
// baseline (185.254 us; speedup 1.0000x reference)
//
#include <hip/hip_runtime.h>
#include <hip/hip_bf16.h>
#include <math.h>

typedef __bf16 bf16_t;
typedef __bf16 bf16x8 __attribute__((ext_vector_type(8)));
typedef float  f32x4  __attribute__((ext_vector_type(4)));
typedef float  f32x16 __attribute__((ext_vector_type(16)));

#define BB 8
#define CC 128
#define NN 4096
#define LDP 136
// 1/sqrt(128) * log2(e)  (attention scale folded into q, softmax in exp2 domain)
#define SCALE2 0.12751743342f

static __device__ __forceinline__ f32x4 mfma16(bf16x8 a, bf16x8 b, f32x4 c) {
    return __builtin_amdgcn_mfma_f32_16x16x32_bf16(a, b, c, 0, 0, 0);
}
static __device__ __forceinline__ f32x16 mfma32(bf16x8 a, bf16x8 b, f32x16 c) {
    return __builtin_amdgcn_mfma_f32_32x32x16_bf16(a, b, c, 0, 0, 0);
}
static __device__ __forceinline__ void gld16(const void* g, void* l) {
    __builtin_amdgcn_global_load_lds(
        (const __attribute__((address_space(1))) void*)g,
        (__attribute__((address_space(3))) void*)l, 16, 0, 0);
}
static __device__ __forceinline__ unsigned pack2bf(float a, float b) {
    union { bf16_t h[2]; unsigned u; } r;
    r.h[0] = (bf16_t)a; r.h[1] = (bf16_t)b;
    return r.u;
}

// ---------------- K1: GroupNorm stats (1024 thr) ----------------
__global__ void __launch_bounds__(1024) gn_stats(const float* __restrict__ in,
                                                 float* __restrict__ stats) {
    int bg = blockIdx.x;
    const float4* p4 = (const float4*)(in + (size_t)bg * 16384);
    int tid = threadIdx.x;
    float s = 0.f, ss = 0.f;
    for (int i = tid; i < 4096; i += 1024) {
        float4 v = p4[i];
        s  += v.x + v.y + v.z + v.w;
        ss += v.x*v.x + v.y*v.y + v.z*v.z + v.w*v.w;
    }
    for (int off = 1; off < 64; off <<= 1) {
        s  += __shfl_xor(s,  off, 64);
        ss += __shfl_xor(ss, off, 64);
    }
    __shared__ float red[32];
    int wv = tid >> 6;
    if ((tid & 63) == 0) { red[wv*2] = s; red[wv*2+1] = ss; }
    __syncthreads();
    if (tid == 0) {
        float S = 0.f, SS = 0.f;
        #pragma unroll
        for (int i = 0; i < 16; i++) { S += red[2*i]; SS += red[2*i+1]; }
        float mu  = S * (1.f/16384.f);
        float var = SS * (1.f/16384.f) - mu*mu;
        stats[bg*2]   = mu;
        stats[bg*2+1] = rsqrtf(var + 1e-5f);
    }
}

// ---------------- K2: fused groupnorm + qkv GEMM + persist xn (bf16). 512 thr, grid 256 --------
// q plain+scaled; k XOR-swizzled (16-group, row&15);
// vT transposed + bit2<->3 j-perm + 16-group XOR swizzle (c&15); xn bf16 [B,C,N] for proj residual.
__global__ void __launch_bounds__(512) qkv_gemm(const float* __restrict__ in,
        const float* __restrict__ stats, const float* __restrict__ gw, const float* __restrict__ gb,
        const float* __restrict__ Wq, const float* __restrict__ bq,
        const float* __restrict__ Wk, const float* __restrict__ bk,
        const float* __restrict__ Wv, const float* __restrict__ bv,
        bf16_t* __restrict__ q, bf16_t* __restrict__ k, bf16_t* __restrict__ vT,
        bf16_t* __restrict__ xn) {
    __shared__ bf16_t wb[CC * LDP];        // 34.8 KB
    __shared__ bf16_t xt[128 * 130];       // 33.3 KB normalized token tile [pixel][chan]
    int b  = blockIdx.x >> 5;
    int n0 = (blockIdx.x & 31) << 7;
    int tid = threadIdx.x;
    int lane = tid & 63, l15 = lane & 15, quad = lane >> 4;
    int w = tid >> 6;                       // 0..7, 16 rows each

    // normalize in-tile -> xt (token-major) + persist bf16 xn [B,C,N]
    for (int i = tid; i < 4096; i += 512) {
        int c = i >> 5, p4 = i & 31;
        const float4* inp = (const float4*)(in + (size_t)(b*CC + c)*NN + n0);
        float4 v = inp[p4];
        int sg = b*32 + (c >> 2);
        float mu = stats[sg*2], rs = stats[sg*2+1];
        float gwc = gw[c], gbc = gb[c];
        float x0 = (v.x - mu)*rs*gwc + gbc;
        float x1 = (v.y - mu)*rs*gwc + gbc;
        float x2 = (v.z - mu)*rs*gwc + gbc;
        float x3 = (v.w - mu)*rs*gwc + gbc;
        xt[(p4*4 + 0)*130 + c] = (bf16_t)x0;
        xt[(p4*4 + 1)*130 + c] = (bf16_t)x1;
        xt[(p4*4 + 2)*130 + c] = (bf16_t)x2;
        xt[(p4*4 + 3)*130 + c] = (bf16_t)x3;
        uint2 pk;
        pk.x = pack2bf(x0, x1);
        pk.y = pack2bf(x2, x3);
        *(uint2*)&xn[(size_t)(b*CC + c)*NN + n0 + p4*4] = pk;
    }
    // stage Wq while xt is being built
    for (int i = tid; i < 2048; i += 512) {
        int row = i >> 4, s8 = i & 15;
        const float* wp = Wq + row*128 + s8*8;
        bf16x8 v;
        #pragma unroll
        for (int j = 0; j < 8; j++) v[j] = (bf16_t)wp[j];
        *(bf16x8*)&wb[row*LDP + s8*8] = v;
    }
    __syncthreads();
    bf16x8 afr[4];
    #pragma unroll
    for (int kb = 0; kb < 4; kb++)
        afr[kb] = *(const bf16x8*)&xt[(w*16 + l15)*130 + kb*32 + quad*8];

    for (int ph = 0; ph < 3; ph++) {
        const float* bs = (ph == 0) ? bq : (ph == 1 ? bk : bv);
        f32x4 acc[8];
        f32x4 z = {0.f, 0.f, 0.f, 0.f};
        #pragma unroll
        for (int t = 0; t < 8; t++) acc[t] = z;
        #pragma unroll
        for (int kb = 0; kb < 4; kb++)
            #pragma unroll
            for (int t = 0; t < 8; t++) {
                bf16x8 bf = *(const bf16x8*)&wb[(t*16 + l15)*LDP + kb*32 + quad*8];
                acc[t] = mfma16(afr[kb], bf, acc[t]);
            }
        __syncthreads();   // all waves done reading W from wb
        if (ph < 2) {
            float sc = (ph == 0) ? SCALE2 : 1.0f;
            #pragma unroll
            for (int t = 0; t < 8; t++) {
                float bias = bs[t*16 + l15];
                #pragma unroll
                for (int r = 0; r < 4; r++) {
                    int nloc = w*16 + quad*4 + r;
                    wb[nloc*LDP + t*16 + l15] = (bf16_t)((acc[t][r] + bias) * sc);
                }
            }
            __syncthreads();
            bf16_t* outp = (ph == 0) ? q : k;
            for (int i = tid; i < 2048; i += 512) {
                int row = i >> 4, g = i & 15;
                bf16x8 vv = *(const bf16x8*)&wb[row*LDP + g*8];
                int gd = (ph == 0) ? g : (g ^ (row & 15));
                *(bf16x8*)&outp[(size_t)(b*NN + n0 + row)*CC + gd*8] = vv;
            }
        } else {
            #pragma unroll
            for (int t = 0; t < 8; t++) {
                float bias = bs[t*16 + l15];
                #pragma unroll
                for (int r = 0; r < 4; r++) {
                    int nloc = w*16 + quad*4 + r;           // vT transpose: [c][nloc]
                    wb[(t*16 + l15)*LDP + nloc] = (bf16_t)(acc[t][r] + bias);
                }
            }
            __syncthreads();
            for (int i = tid; i < 8192; i += 512) {
                int c = i >> 6, np = i & 63;   // np = pair index (n = 2*np)
                unsigned int d = *(const unsigned int*)&wb[c*LDP + np*2];
                // bit2<->3 swap of n == bit1<->2 swap of np (PV B-frag identity perm)
                int npp = (np & ~6) | ((np & 2) << 1) | ((np & 4) >> 1);
                int g = (npp >> 2) ^ (c & 15);            // 16-group XOR bank swizzle
                *(unsigned int*)&vT[(size_t)(b*CC + c)*NN + n0 + (g << 3) + ((npp & 3) << 1)] = d;
            }
        }
        if (ph < 2) {   // stage next W
            __syncthreads();
            const float* Wn = (ph == 0) ? Wk : Wv;
            for (int i = tid; i < 2048; i += 512) {
                int row = i >> 4, s8 = i & 15;
                const float* wp = Wn + row*128 + s8*8;
                bf16x8 v;
                #pragma unroll
                for (int j = 0; j < 8; j++) v[j] = (bf16_t)wp[j];
                *(bf16x8*)&wb[row*LDP + s8*8] = v;
            }
            __syncthreads();
        }
    }
}

// ---------------- K3: flash, 128-j single-buffered tiles, 64 KB LDS -> 2 blocks/CU --------------
// grid 512: b = blk>>6, qb = (blk>>2)&15 (256 q-rows), jq = blk&3 (1024 j, 8 iters of 128).
// Cross-block overlap covers the staging stall (no intra-block dbuf).
__global__ void __launch_bounds__(512, 2) flash_attn(const bf16_t* __restrict__ qg_,
                                                     const bf16_t* __restrict__ kg,
                                                     const bf16_t* __restrict__ vg,
                                                     unsigned* __restrict__ opd,
                                                     float* __restrict__ mlf) {
    __shared__ bf16_t kbuf[128*128];      // 32 KB, [j][c], 16-group XOR
    __shared__ bf16_t vbuf[128*128];      // 32 KB, [c][j'], perm+XOR pre-applied in global
    const int b    = blockIdx.x >> 6;
    const int qb   = (blockIdx.x >> 2) & 15;
    const int jq   = blockIdx.x & 3;
    const int q0   = qb << 8;
    const int j00  = jq << 10;
    const int tid  = threadIdx.x;
    const int lane = tid & 63;
    const int l31  = lane & 31;
    const int h    = lane >> 5;
    const int w    = tid >> 6;            // 0..7

    bf16x8 qf[8];
    {
        const bf16_t* qr = qg_ + ((size_t)(b*NN + q0 + w*32 + l31))*CC + h*8;
        #pragma unroll
        for (int kc = 0; kc < 8; kc++) qf[kc] = *(const bf16x8*)(qr + kc*16);
    }
    int gofs[8];
    #pragma unroll
    for (int kc = 0; kc < 8; kc++) gofs[kc] = ((2*kc + h) ^ (l31 & 15)) << 3;

    f32x16 ot[4];
    #pragma unroll
    for (int ct = 0; ct < 4; ct++)
        #pragma unroll
        for (int r = 0; r < 16; r++) ot[ct][r] = 0.f;
    float l = 0.f;

    // stage tile 0
    {
        const bf16_t* kt = kg + ((size_t)(b*NN + j00))*CC;
        #pragma unroll
        for (int it = 0; it < 4; it++) {
            int cb = it*512 + tid;
            gld16(kt + (size_t)cb*8, &kbuf[cb*8]);
        }
        #pragma unroll
        for (int it = 0; it < 4; it++) {
            int c = it*512 + tid;
            gld16(vg + ((size_t)(b*CC + (c >> 4)))*NN + j00 + (c & 15)*8, &vbuf[c*8]);
        }
    }
    __syncthreads();

    for (int i = 0; i < 8; i++) {
        // S^T: 4 independent accumulator chains (kc outer, tt inner)
        f32x16 st[4];
        #pragma unroll
        for (int tt = 0; tt < 4; tt++)
            #pragma unroll
            for (int r = 0; r < 16; r++) st[tt][r] = 0.f;
        #pragma unroll
        for (int kc = 0; kc < 8; kc++) {
            #pragma unroll
            for (int tt = 0; tt < 4; tt++) {
                bf16x8 kf = *(const bf16x8*)&kbuf[(tt*32 + l31)*128 + gofs[kc]];
                st[tt] = mfma32(kf, qf[kc], st[tt]);
            }
        }
        // per-tt: maxless softmax (exp2, tree sum, pack) then PV
        #pragma unroll
        for (int tt = 0; tt < 4; tt++) {
            #pragma unroll
            for (int r = 0; r < 16; r++) st[tt][r] = __builtin_amdgcn_exp2f(st[tt][r]);
            {
                float a0 = (st[tt][0]+st[tt][1]) + (st[tt][2]+st[tt][3]);
                float a1 = (st[tt][4]+st[tt][5]) + (st[tt][6]+st[tt][7]);
                float a2 = (st[tt][8]+st[tt][9]) + (st[tt][10]+st[tt][11]);
                float a3 = (st[tt][12]+st[tt][13]) + (st[tt][14]+st[tt][15]);
                l += (a0 + a1) + (a2 + a3);
            }
            union { unsigned u[4]; bf16x8 v; } pf[2];
            #pragma unroll
            for (int kcl = 0; kcl < 2; kcl++)
                #pragma unroll
                for (int g = 0; g < 4; g++)
                    pf[kcl].u[g] = pack2bf(st[tt][8*kcl + 2*g], st[tt][8*kcl + 2*g + 1]);
            #pragma unroll
            for (int kcl = 0; kcl < 2; kcl++) {
                const int kc = tt*2 + kcl;
                #pragma unroll
                for (int ct = 0; ct < 4; ct++) {
                    bf16x8 vf = *(const bf16x8*)&vbuf[(ct*32 + l31)*128 + gofs[kc]];
                    ot[ct] = mfma32(vf, pf[kcl].v, ot[ct]);
                }
            }
        }
        if (i < 7) {
            __syncthreads();               // all waves done reading current tile
            const int j0n = j00 + ((i + 1) << 7);
            const bf16_t* kt = kg + ((size_t)(b*NN + j0n))*CC;
            #pragma unroll
            for (int it = 0; it < 4; it++) {
                int cb = it*512 + tid;
                gld16(kt + (size_t)cb*8, &kbuf[cb*8]);
            }
            #pragma unroll
            for (int it = 0; it < 4; it++) {
                int c = it*512 + tid;
                gld16(vg + ((size_t)(b*CC + (c >> 4)))*NN + j0n + (c & 15)*8, &vbuf[c*8]);
            }
            __syncthreads();               // staging visible (vmcnt drained)
        }
    }
    // epilogue: combine lane^32 halves of l; store packed bf16 partials [cpair][q]
    l += __shfl_xor(l, 32, 64);
    const int row0 = q0 + w*32 + l31;
    unsigned* ob = opd + ((size_t)(jq*BB + b)) * 64 * NN;
    #pragma unroll
    for (int ct = 0; ct < 4; ct++)
        #pragma unroll
        for (int rp = 0; rp < 8; rp++) {
            int cpair = ct*16 + (rp & 1) + 4*(rp >> 1) + 2*h;
            ob[(size_t)cpair*NN + row0] = pack2bf(ot[ct][2*rp], ot[ct][2*rp + 1]);
        }
    if (h == 0)
        mlf[((size_t)(jq*BB + b))*NN + row0] = l;
}

// ---------------- K4: fused merge(4 parts) + proj GEMM + bf16-normed residual. 512 thr ----------
__global__ void __launch_bounds__(512) proj_out(const unsigned* __restrict__ opd,
                                                const float* __restrict__ mlf,
                                                const float* __restrict__ Wp,
                                                const float* __restrict__ bp,
                                                const bf16_t* __restrict__ xn,
                                                float* __restrict__ out) {
    __shared__ bf16_t wb[CC * LDP];       // 34.8 KB
    __shared__ bf16_t aot[128 * 130];     // 33.3 KB merged ao tile [q][c]
    __shared__ float invl[128];
    int b  = blockIdx.x >> 5;
    int n0 = (blockIdx.x & 31) << 7;
    int tid = threadIdx.x;
    int lane = tid & 63, l15 = lane & 15, quad = lane >> 4;
    int w = tid >> 6;                      // 0..7, 16 rows each
    if (tid < 128) {
        float lt = 0.f;
        #pragma unroll
        for (int p = 0; p < 4; p++) lt += mlf[((size_t)(p*BB + b))*NN + n0 + tid];
        invl[tid] = 1.0f / lt;
    }
    for (int i = tid; i < 2048; i += 512) {
        int row = i >> 4, s8 = i & 15;
        const float* wp = Wp + row*128 + s8*8;
        bf16x8 v;
        #pragma unroll
        for (int j = 0; j < 8; j++) v[j] = (bf16_t)wp[j];
        *(bf16x8*)&wb[row*LDP + s8*8] = v;
    }
    __syncthreads();
    // merge 4 j-part partials -> aot
    for (int i = tid; i < 8192; i += 512) {
        int qq = i & 127, cp = i >> 7;
        float lo = 0.f, hi = 0.f;
        #pragma unroll
        for (int p = 0; p < 4; p++) {
            unsigned u = opd[(((size_t)(p*BB + b))*64 + cp)*NN + n0 + qq];
            union { unsigned u; float f; } a, c;
            a.u = u << 16; c.u = u & 0xffff0000u;
            lo += a.f; hi += c.f;
        }
        float s = invl[qq];
        *(unsigned*)&aot[qq*130 + cp*2] = pack2bf(lo * s, hi * s);
    }
    __syncthreads();
    bf16x8 afr[4];
    #pragma unroll
    for (int kb = 0; kb < 4; kb++)
        afr[kb] = *(const bf16x8*)&aot[(w*16 + l15)*130 + kb*32 + quad*8];
    f32x4 acc[8];
    f32x4 z = {0.f, 0.f, 0.f, 0.f};
    #pragma unroll
    for (int t = 0; t < 8; t++) acc[t] = z;
    #pragma unroll
    for (int kb = 0; kb < 4; kb++)
        #pragma unroll
        for (int t = 0; t < 8; t++) {
            bf16x8 bf = *(const bf16x8*)&wb[(t*16 + l15)*LDP + kb*32 + quad*8];
            acc[t] = mfma16(afr[kb], bf, acc[t]);
        }
    __syncthreads();
    #pragma unroll
    for (int t = 0; t < 8; t++) {
        float bias = bp[t*16 + l15];
        #pragma unroll
        for (int r = 0; r < 4; r++) {
            int nloc = w*16 + quad*4 + r;
            wb[(t*16 + l15)*LDP + nloc] = (bf16_t)(acc[t][r] + bias);
        }
    }
    __syncthreads();
    for (int i = tid; i < 8192; i += 512) {
        int c = i >> 6, np = i & 63;
        bf16_t b0 = wb[c*LDP + np*2], b1 = wb[c*LDP + np*2 + 1];
        size_t idx = (size_t)(b*CC + c)*NN + n0 + np*2;
        unsigned xu = *(const unsigned*)&xn[idx];
        union { unsigned u; float f; } x0, x1;
        x0.u = xu << 16; x1.u = xu & 0xffff0000u;
        float2 ov;
        ov.x = x0.f + (float)b0;
        ov.y = x1.f + (float)b1;
        *(float2*)&out[idx] = ov;
    }
}

extern "C" void kernel_launch(void* const* d_in, const int* in_sizes, int n_in,
                              void* d_out, int out_size, void* d_ws, size_t ws_size,
                              hipStream_t stream) {
    const float* in = (const float*)d_in[0];
    const float* gw = (const float*)d_in[1];
    const float* gb = (const float*)d_in[2];
    const float* Wq = (const float*)d_in[3];
    const float* bq = (const float*)d_in[4];
    const float* Wk = (const float*)d_in[5];
    const float* bk = (const float*)d_in[6];
    const float* Wv = (const float*)d_in[7];
    const float* bv = (const float*)d_in[8];
    const float* Wp = (const float*)d_in[9];
    const float* bp = (const float*)d_in[10];
    float* out = (float*)d_out;

    char* ws = (char*)d_ws;
    const size_t SZ = (size_t)BB * NN * CC * 2;        // 8.39 MB
    float*    stats = (float*)ws;
    bf16_t*   q  = (bf16_t*)(ws + 2048);
    bf16_t*   kk = (bf16_t*)(ws + 2048 + SZ);
    bf16_t*   vT = (bf16_t*)(ws + 2048 + 2*SZ);
    bf16_t*   xn = (bf16_t*)(ws + 2048 + 3*SZ);
    unsigned* op = (unsigned*)(ws + 2048 + 4*SZ);      // 33.55 MB packed-bf16 partials (4 parts)
    float*    ml = (float*)(ws + 2048 + 4*SZ + (size_t)4*BB*64*NN*4);

    gn_stats  <<<256, 1024, 0, stream>>>(in, stats);
    qkv_gemm  <<<256,  512, 0, stream>>>(in, stats, gw, gb, Wq, bq, Wk, bk, Wv, bv, q, kk, vT, xn);
    flash_attn<<<512,  512, 0, stream>>>(q, kk, vT, op, ml);
    proj_out  <<<256,  512, 0, stream>>>(op, ml, Wp, bp, xn, out);
}

// Round 14
// 180.929 us; speedup vs baseline: 1.0239x; 1.0239x over previous
//
#include <hip/hip_runtime.h>
#include <hip/hip_bf16.h>
#include <math.h>

typedef __bf16 bf16_t;
typedef __bf16 bf16x8 __attribute__((ext_vector_type(8)));
typedef float  f32x4  __attribute__((ext_vector_type(4)));
typedef float  f32x16 __attribute__((ext_vector_type(16)));

#define BB 8
#define CC 128
#define NN 4096
#define LDP 136
// 1/sqrt(128) * log2(e)  (attention scale folded into q, softmax in exp2 domain)
#define SCALE2 0.12751743342f

static __device__ __forceinline__ f32x4 mfma16(bf16x8 a, bf16x8 b, f32x4 c) {
    return __builtin_amdgcn_mfma_f32_16x16x32_bf16(a, b, c, 0, 0, 0);
}
static __device__ __forceinline__ f32x16 mfma32(bf16x8 a, bf16x8 b, f32x16 c) {
    return __builtin_amdgcn_mfma_f32_32x32x16_bf16(a, b, c, 0, 0, 0);
}
static __device__ __forceinline__ void gld16(const void* g, void* l) {
    __builtin_amdgcn_global_load_lds(
        (const __attribute__((address_space(1))) void*)g,
        (__attribute__((address_space(3))) void*)l, 16, 0, 0);
}
static __device__ __forceinline__ unsigned pack2bf(float a, float b) {
    union { bf16_t h[2]; unsigned u; } r;
    r.h[0] = (bf16_t)a; r.h[1] = (bf16_t)b;
    return r.u;
}

// ---------------- K1: GroupNorm stats (1024 thr) ----------------
__global__ void __launch_bounds__(1024) gn_stats(const float* __restrict__ in,
                                                 float* __restrict__ stats) {
    int bg = blockIdx.x;
    const float4* p4 = (const float4*)(in + (size_t)bg * 16384);
    int tid = threadIdx.x;
    float s = 0.f, ss = 0.f;
    for (int i = tid; i < 4096; i += 1024) {
        float4 v = p4[i];
        s  += v.x + v.y + v.z + v.w;
        ss += v.x*v.x + v.y*v.y + v.z*v.z + v.w*v.w;
    }
    for (int off = 1; off < 64; off <<= 1) {
        s  += __shfl_xor(s,  off, 64);
        ss += __shfl_xor(ss, off, 64);
    }
    __shared__ float red[32];
    int wv = tid >> 6;
    if ((tid & 63) == 0) { red[wv*2] = s; red[wv*2+1] = ss; }
    __syncthreads();
    if (tid == 0) {
        float S = 0.f, SS = 0.f;
        #pragma unroll
        for (int i = 0; i < 16; i++) { S += red[2*i]; SS += red[2*i+1]; }
        float mu  = S * (1.f/16384.f);
        float var = SS * (1.f/16384.f) - mu*mu;
        stats[bg*2]   = mu;
        stats[bg*2+1] = rsqrtf(var + 1e-5f);
    }
}

// ---------------- K2: fused groupnorm + qkv GEMM + persist xn. 256 thr, grid 512 ----------------
// 64-row tiles -> ~51 KB LDS -> 2-3 blocks/CU co-resident (barriers overlap across blocks).
// q plain+scaled; k XOR-swizzled (16-group, row&15);
// vT transposed + bit2<->3 j-perm + 16-group XOR over 128-j segments (g128 = local_g + 8*half).
__global__ void __launch_bounds__(256) qkv_gemm(const float* __restrict__ in,
        const float* __restrict__ stats, const float* __restrict__ gw, const float* __restrict__ gb,
        const float* __restrict__ Wq, const float* __restrict__ bq,
        const float* __restrict__ Wk, const float* __restrict__ bk,
        const float* __restrict__ Wv, const float* __restrict__ bv,
        bf16_t* __restrict__ q, bf16_t* __restrict__ k, bf16_t* __restrict__ vT,
        bf16_t* __restrict__ xn) {
    __shared__ bf16_t wb[CC * LDP];        // 34.8 KB
    __shared__ bf16_t xt[64 * 130];        // 16.6 KB normalized token tile [pixel][chan]
    int b  = blockIdx.x >> 6;
    int n0 = (blockIdx.x & 63) << 6;
    int tid = threadIdx.x;
    int lane = tid & 63, l15 = lane & 15, quad = lane >> 4;
    int w = tid >> 6;                       // 0..3, 16 rows each

    // normalize 64-pixel in-tile -> xt (token-major) + persist bf16 xn [B,C,N]
    for (int i = tid; i < 2048; i += 256) {
        int c = i >> 4, p4 = i & 15;
        const float4* inp = (const float4*)(in + (size_t)(b*CC + c)*NN + n0);
        float4 v = inp[p4];
        int sg = b*32 + (c >> 2);
        float mu = stats[sg*2], rs = stats[sg*2+1];
        float gwc = gw[c], gbc = gb[c];
        float x0 = (v.x - mu)*rs*gwc + gbc;
        float x1 = (v.y - mu)*rs*gwc + gbc;
        float x2 = (v.z - mu)*rs*gwc + gbc;
        float x3 = (v.w - mu)*rs*gwc + gbc;
        xt[(p4*4 + 0)*130 + c] = (bf16_t)x0;
        xt[(p4*4 + 1)*130 + c] = (bf16_t)x1;
        xt[(p4*4 + 2)*130 + c] = (bf16_t)x2;
        xt[(p4*4 + 3)*130 + c] = (bf16_t)x3;
        uint2 pk;
        pk.x = pack2bf(x0, x1);
        pk.y = pack2bf(x2, x3);
        *(uint2*)&xn[(size_t)(b*CC + c)*NN + n0 + p4*4] = pk;
    }
    // stage Wq
    for (int i = tid; i < 2048; i += 256) {
        int row = i >> 4, s8 = i & 15;
        const float* wp = Wq + row*128 + s8*8;
        bf16x8 v;
        #pragma unroll
        for (int j = 0; j < 8; j++) v[j] = (bf16_t)wp[j];
        *(bf16x8*)&wb[row*LDP + s8*8] = v;
    }
    __syncthreads();
    bf16x8 afr[4];
    #pragma unroll
    for (int kb = 0; kb < 4; kb++)
        afr[kb] = *(const bf16x8*)&xt[(w*16 + l15)*130 + kb*32 + quad*8];

    for (int ph = 0; ph < 3; ph++) {
        const float* bs = (ph == 0) ? bq : (ph == 1 ? bk : bv);
        f32x4 acc[8];
        f32x4 z = {0.f, 0.f, 0.f, 0.f};
        #pragma unroll
        for (int t = 0; t < 8; t++) acc[t] = z;
        #pragma unroll
        for (int kb = 0; kb < 4; kb++)
            #pragma unroll
            for (int t = 0; t < 8; t++) {
                bf16x8 bf = *(const bf16x8*)&wb[(t*16 + l15)*LDP + kb*32 + quad*8];
                acc[t] = mfma16(afr[kb], bf, acc[t]);
            }
        __syncthreads();   // all waves done reading W from wb
        if (ph < 2) {
            float sc = (ph == 0) ? SCALE2 : 1.0f;
            #pragma unroll
            for (int t = 0; t < 8; t++) {
                float bias = bs[t*16 + l15];
                #pragma unroll
                for (int r = 0; r < 4; r++) {
                    int nloc = w*16 + quad*4 + r;
                    wb[nloc*LDP + t*16 + l15] = (bf16_t)((acc[t][r] + bias) * sc);
                }
            }
            __syncthreads();
            bf16_t* outp = (ph == 0) ? q : k;
            for (int i = tid; i < 1024; i += 256) {
                int row = i >> 4, g = i & 15;
                bf16x8 vv = *(const bf16x8*)&wb[row*LDP + g*8];
                int gd = (ph == 0) ? g : (g ^ (row & 15));
                *(bf16x8*)&outp[(size_t)(b*NN + n0 + row)*CC + gd*8] = vv;
            }
        } else {
            #pragma unroll
            for (int t = 0; t < 8; t++) {
                float bias = bs[t*16 + l15];
                #pragma unroll
                for (int r = 0; r < 4; r++) {
                    int nloc = w*16 + quad*4 + r;           // vT transpose: [c][nloc]
                    wb[(t*16 + l15)*LDP + nloc] = (bf16_t)(acc[t][r] + bias);
                }
            }
            __syncthreads();
            int half8 = (n0 >> 3) & 8;                      // 8*half of the 128-j segment
            size_t nseg = n0 & ~127;
            for (int i = tid; i < 4096; i += 256) {
                int c = i >> 5, np = i & 31;   // np = local pair index (jloc = 2*np)
                unsigned int d = *(const unsigned int*)&wb[c*LDP + np*2];
                // bit2<->3 swap of j == bit1<->2 swap of np (PV B-frag identity perm)
                int npp = (np & ~6) | ((np & 2) << 1) | ((np & 4) >> 1);
                int g128 = (npp >> 2) + half8;
                int gs = g128 ^ (c & 15);                   // 16-group XOR over 128-j segment
                *(unsigned int*)&vT[(size_t)(b*CC + c)*NN + nseg + (gs << 3) + ((npp & 3) << 1)] = d;
            }
        }
        if (ph < 2) {   // stage next W
            __syncthreads();
            const float* Wn = (ph == 0) ? Wk : Wv;
            for (int i = tid; i < 2048; i += 256) {
                int row = i >> 4, s8 = i & 15;
                const float* wp = Wn + row*128 + s8*8;
                bf16x8 v;
                #pragma unroll
                for (int j = 0; j < 8; j++) v[j] = (bf16_t)wp[j];
                *(bf16x8*)&wb[row*LDP + s8*8] = v;
            }
            __syncthreads();
        }
    }
}

// ---------------- K3: flash (R9-exact, 67.6 us), 512 thr (2 waves/SIMD), 32 q-rows/wave ----------
// grid 256: b = blk>>5, qb = (blk>>1)&15 (256 q-rows), jh = blk&1 (2048 j, 16 iters of 128).
__global__ void __launch_bounds__(512, 2) flash_attn(const bf16_t* __restrict__ qg_,
                                                     const bf16_t* __restrict__ kg,
                                                     const bf16_t* __restrict__ vg,
                                                     unsigned* __restrict__ opd,
                                                     float* __restrict__ mlf) {
    __shared__ bf16_t kbuf[2][128*128];   // 64 KB
    __shared__ bf16_t vbuf[2][128*128];   // 64 KB
    const int b    = blockIdx.x >> 5;
    const int qb   = (blockIdx.x >> 1) & 15;
    const int jh   = blockIdx.x & 1;
    const int q0   = qb << 8;
    const int j00  = jh << 11;
    const int tid  = threadIdx.x;
    const int lane = tid & 63;
    const int l31  = lane & 31;
    const int h    = lane >> 5;
    const int w    = tid >> 6;            // 0..7

    bf16x8 qf[8];
    {
        const bf16_t* qr = qg_ + ((size_t)(b*NN + q0 + w*32 + l31))*CC + h*8;
        #pragma unroll
        for (int kc = 0; kc < 8; kc++) qf[kc] = *(const bf16x8*)(qr + kc*16);
    }
    int gofs[8];
    #pragma unroll
    for (int kc = 0; kc < 8; kc++) gofs[kc] = ((2*kc + h) ^ (l31 & 15)) << 3;

    f32x16 ot[4];
    #pragma unroll
    for (int ct = 0; ct < 4; ct++)
        #pragma unroll
        for (int r = 0; r < 16; r++) ot[ct][r] = 0.f;
    float l = 0.f;

    {
        const bf16_t* kt = kg + ((size_t)(b*NN + j00))*CC;
        #pragma unroll
        for (int it = 0; it < 4; it++) {
            int cb = it*512 + tid;
            gld16(kt + (size_t)cb*8, &kbuf[0][cb*8]);
        }
        #pragma unroll
        for (int it = 0; it < 4; it++) {
            int c = it*512 + tid;
            gld16(vg + ((size_t)(b*CC + (c >> 4)))*NN + j00 + (c & 15)*8, &vbuf[0][c*8]);
        }
    }
    __syncthreads();

    for (int i = 0; i < 16; i++) {
        const int cur = i & 1;
        if (i < 15) {                      // prefetch next tile (drained by end barrier)
            const int j0n = j00 + ((i + 1) << 7);
            const bf16_t* kt = kg + ((size_t)(b*NN + j0n))*CC;
            #pragma unroll
            for (int it = 0; it < 4; it++) {
                int cb = it*512 + tid;
                gld16(kt + (size_t)cb*8, &kbuf[cur^1][cb*8]);
            }
            #pragma unroll
            for (int it = 0; it < 4; it++) {
                int c = it*512 + tid;
                gld16(vg + ((size_t)(b*CC + (c >> 4)))*NN + j0n + (c & 15)*8, &vbuf[cur^1][c*8]);
            }
        }
        // S^T: 4 independent accumulator chains (kc outer, tt inner)
        f32x16 st[4];
        #pragma unroll
        for (int tt = 0; tt < 4; tt++)
            #pragma unroll
            for (int r = 0; r < 16; r++) st[tt][r] = 0.f;
        #pragma unroll
        for (int kc = 0; kc < 8; kc++) {
            #pragma unroll
            for (int tt = 0; tt < 4; tt++) {
                bf16x8 kf = *(const bf16x8*)&kbuf[cur][(tt*32 + l31)*128 + gofs[kc]];
                st[tt] = mfma32(kf, qf[kc], st[tt]);
            }
        }
        // per-tt: maxless softmax (exp2, tree sum, pack) then PV
        #pragma unroll
        for (int tt = 0; tt < 4; tt++) {
            #pragma unroll
            for (int r = 0; r < 16; r++) st[tt][r] = __builtin_amdgcn_exp2f(st[tt][r]);
            {
                float a0 = (st[tt][0]+st[tt][1]) + (st[tt][2]+st[tt][3]);
                float a1 = (st[tt][4]+st[tt][5]) + (st[tt][6]+st[tt][7]);
                float a2 = (st[tt][8]+st[tt][9]) + (st[tt][10]+st[tt][11]);
                float a3 = (st[tt][12]+st[tt][13]) + (st[tt][14]+st[tt][15]);
                l += (a0 + a1) + (a2 + a3);
            }
            union { unsigned u[4]; bf16x8 v; } pf[2];
            #pragma unroll
            for (int kcl = 0; kcl < 2; kcl++)
                #pragma unroll
                for (int g = 0; g < 4; g++)
                    pf[kcl].u[g] = pack2bf(st[tt][8*kcl + 2*g], st[tt][8*kcl + 2*g + 1]);
            #pragma unroll
            for (int kcl = 0; kcl < 2; kcl++) {
                const int kc = tt*2 + kcl;
                #pragma unroll
                for (int ct = 0; ct < 4; ct++) {
                    bf16x8 vf = *(const bf16x8*)&vbuf[cur][(ct*32 + l31)*128 + gofs[kc]];
                    ot[ct] = mfma32(vf, pf[kcl].v, ot[ct]);
                }
            }
        }
        __syncthreads();
    }
    l += __shfl_xor(l, 32, 64);
    const int row0 = q0 + w*32 + l31;
    unsigned* ob = opd + ((size_t)(jh*BB + b)) * 64 * NN;
    #pragma unroll
    for (int ct = 0; ct < 4; ct++)
        #pragma unroll
        for (int rp = 0; rp < 8; rp++) {
            int cpair = ct*16 + (rp & 1) + 4*(rp >> 1) + 2*h;
            ob[(size_t)cpair*NN + row0] = pack2bf(ot[ct][2*rp], ot[ct][2*rp + 1]);
        }
    if (h == 0)
        mlf[((size_t)(jh*BB + b))*NN + row0] = l;
}

// ---------------- K4: fused merge(2) + proj GEMM + bf16 residual. 256 thr, grid 512 ------------
__global__ void __launch_bounds__(256) proj_out(const unsigned* __restrict__ opd,
                                                const float* __restrict__ mlf,
                                                const float* __restrict__ Wp,
                                                const float* __restrict__ bp,
                                                const bf16_t* __restrict__ xn,
                                                float* __restrict__ out) {
    __shared__ bf16_t wb[CC * LDP];       // 34.8 KB
    __shared__ bf16_t aot[64 * 130];      // 16.6 KB merged ao tile [q][c]
    __shared__ float invl[64];
    int b  = blockIdx.x >> 6;
    int n0 = (blockIdx.x & 63) << 6;
    int tid = threadIdx.x;
    int lane = tid & 63, l15 = lane & 15, quad = lane >> 4;
    int w = tid >> 6;                      // 0..3, 16 rows each
    if (tid < 64) {
        float lt = mlf[(size_t)b*NN + n0 + tid] + mlf[((size_t)(BB + b))*NN + n0 + tid];
        invl[tid] = 1.0f / lt;
    }
    for (int i = tid; i < 2048; i += 256) {
        int row = i >> 4, s8 = i & 15;
        const float* wp = Wp + row*128 + s8*8;
        bf16x8 v;
        #pragma unroll
        for (int j = 0; j < 8; j++) v[j] = (bf16_t)wp[j];
        *(bf16x8*)&wb[row*LDP + s8*8] = v;
    }
    __syncthreads();
    // merge 2 j-part partials -> aot
    for (int i = tid; i < 4096; i += 256) {
        int qq = i & 63, cp = i >> 6;
        unsigned u0 = opd[((size_t)b*64 + cp)*NN + n0 + qq];
        unsigned u1 = opd[(((size_t)(BB + b))*64 + cp)*NN + n0 + qq];
        union { unsigned u; float f; } a0, c0, a1, c1;
        a0.u = u0 << 16; c0.u = u0 & 0xffff0000u;
        a1.u = u1 << 16; c1.u = u1 & 0xffff0000u;
        float s = invl[qq];
        *(unsigned*)&aot[qq*130 + cp*2] = pack2bf((a0.f + a1.f) * s, (c0.f + c1.f) * s);
    }
    __syncthreads();
    bf16x8 afr[4];
    #pragma unroll
    for (int kb = 0; kb < 4; kb++)
        afr[kb] = *(const bf16x8*)&aot[(w*16 + l15)*130 + kb*32 + quad*8];
    f32x4 acc[8];
    f32x4 z = {0.f, 0.f, 0.f, 0.f};
    #pragma unroll
    for (int t = 0; t < 8; t++) acc[t] = z;
    #pragma unroll
    for (int kb = 0; kb < 4; kb++)
        #pragma unroll
        for (int t = 0; t < 8; t++) {
            bf16x8 bf = *(const bf16x8*)&wb[(t*16 + l15)*LDP + kb*32 + quad*8];
            acc[t] = mfma16(afr[kb], bf, acc[t]);
        }
    __syncthreads();
    #pragma unroll
    for (int t = 0; t < 8; t++) {
        float bias = bp[t*16 + l15];
        #pragma unroll
        for (int r = 0; r < 4; r++) {
            int nloc = w*16 + quad*4 + r;
            wb[(t*16 + l15)*LDP + nloc] = (bf16_t)(acc[t][r] + bias);
        }
    }
    __syncthreads();
    for (int i = tid; i < 4096; i += 256) {
        int c = i >> 5, np = i & 31;
        bf16_t b0 = wb[c*LDP + np*2], b1 = wb[c*LDP + np*2 + 1];
        size_t idx = (size_t)(b*CC + c)*NN + n0 + np*2;
        unsigned xu = *(const unsigned*)&xn[idx];
        union { unsigned u; float f; } x0, x1;
        x0.u = xu << 16; x1.u = xu & 0xffff0000u;
        float2 ov;
        ov.x = x0.f + (float)b0;
        ov.y = x1.f + (float)b1;
        *(float2*)&out[idx] = ov;
    }
}

extern "C" void kernel_launch(void* const* d_in, const int* in_sizes, int n_in,
                              void* d_out, int out_size, void* d_ws, size_t ws_size,
                              hipStream_t stream) {
    const float* in = (const float*)d_in[0];
    const float* gw = (const float*)d_in[1];
    const float* gb = (const float*)d_in[2];
    const float* Wq = (const float*)d_in[3];
    const float* bq = (const float*)d_in[4];
    const float* Wk = (const float*)d_in[5];
    const float* bk = (const float*)d_in[6];
    const float* Wv = (const float*)d_in[7];
    const float* bv = (const float*)d_in[8];
    const float* Wp = (const float*)d_in[9];
    const float* bp = (const float*)d_in[10];
    float* out = (float*)d_out;

    char* ws = (char*)d_ws;
    const size_t SZ = (size_t)BB * NN * CC * 2;        // 8.39 MB
    float*    stats = (float*)ws;
    bf16_t*   q  = (bf16_t*)(ws + 2048);
    bf16_t*   kk = (bf16_t*)(ws + 2048 + SZ);
    bf16_t*   vT = (bf16_t*)(ws + 2048 + 2*SZ);
    bf16_t*   xn = (bf16_t*)(ws + 2048 + 3*SZ);
    unsigned* op = (unsigned*)(ws + 2048 + 4*SZ);      // 16.78 MB packed-bf16 partials (2 parts)
    float*    ml = (float*)(ws + 2048 + 4*SZ + (size_t)2*BB*64*NN*4);

    gn_stats  <<<256, 1024, 0, stream>>>(in, stats);
    qkv_gemm  <<<512,  256, 0, stream>>>(in, stats, gw, gb, Wq, bq, Wk, bk, Wv, bv, q, kk, vT, xn);
    flash_attn<<<256,  512, 0, stream>>>(q, kk, vT, op, ml);
    proj_out  <<<512,  256, 0, stream>>>(op, ml, Wp, bp, xn, out);
}